// Round 3
// baseline (1188.607 us; speedup 1.0000x reference)
//
#include <hip/hip_runtime.h>

#define NB 32  // batch size B (fixed by problem)
// NOTE: packs dst%32 into bits [20:25) of the edge record => requires N <= 2^20.

// ---------------------------------------------------------------------------
// x (B, N) -> xt (N, B): 32x32 LDS tile transpose, coalesced read and write.
// ---------------------------------------------------------------------------
__global__ void transpose_x_kernel(const float* __restrict__ x,
                                   float* __restrict__ xt, int N) {
    __shared__ float tile[32][33];
    int n0 = blockIdx.x * 32;
    for (int i = threadIdx.y; i < 32; i += 8) {
        int n = n0 + threadIdx.x;
        tile[i][threadIdx.x] = (n < N) ? x[(size_t)i * N + n] : 0.f;
    }
    __syncthreads();
    for (int i = threadIdx.y; i < 32; i += 8) {
        int n = n0 + i;
        if (n < N) xt[(size_t)n * NB + threadIdx.x] = tile[threadIdx.x][i];
    }
}

// ---------------------------------------------------------------------------
// Histogram over buckets (bucket = dst>>5). 3125 counters, L2-resident.
// ---------------------------------------------------------------------------
__global__ void hist_kernel(const int* __restrict__ dst,
                            int* __restrict__ bcount, int nnz) {
    int i = blockIdx.x * blockDim.x + threadIdx.x;
    if (i < nnz) atomicAdd(&bcount[dst[i] >> 5], 1);
}

// ---------------------------------------------------------------------------
// Single-block exclusive scan over nb (<= 256*16) bucket counts.
// Writes boff[0..nb] (boff[nb]=nnz) and initializes cursor = boff.
// ---------------------------------------------------------------------------
__global__ void scan_kernel(const int* __restrict__ bcount,
                            int* __restrict__ boff, int* __restrict__ cursor,
                            int nb, int nnz) {
    __shared__ int lds[256];
    int t = threadIdx.x;
    int chunk = (nb + 255) / 256;
    int base = t * chunk;
    int v[16];  // chunk <= 16 for nb <= 4096
    int s = 0;
    for (int j = 0; j < chunk; j++) {
        int idx = base + j;
        v[j] = (idx < nb) ? bcount[idx] : 0;
        s += v[j];
    }
    lds[t] = s;
    __syncthreads();
    for (int d = 1; d < 256; d <<= 1) {
        int u = (t >= d) ? lds[t - d] : 0;
        __syncthreads();
        lds[t] += u;
        __syncthreads();
    }
    int ex = lds[t] - s;
    for (int j = 0; j < chunk; j++) {
        int idx = base + j;
        if (idx < nb) {
            boff[idx] = ex;
            cursor[idx] = ex;
            ex += v[j];
        }
    }
    if (t == 255) boff[nb] = nnz;
}

// ---------------------------------------------------------------------------
// Partition edges into dst-buckets. Writes are append-sequential per bucket
// (~3125 active 64B lines, L2-resident) => no write amplification.
// Record: {src | (dst%32)<<20, float_bits(val)}.
// ---------------------------------------------------------------------------
__global__ void partition_kernel(const int* __restrict__ src,
                                 const int* __restrict__ dst,
                                 const float* __restrict__ vals,
                                 int* __restrict__ cursor,
                                 int2* __restrict__ bedge, int nnz) {
    int i = blockIdx.x * blockDim.x + threadIdx.x;
    if (i < nnz) {
        int d = dst[i];
        int k = d >> 5;
        int dloc = d & 31;
        int pos = atomicAdd(&cursor[k], 1);
        bedge[pos] = make_int2(src[i] | (dloc << 20), __float_as_int(vals[i]));
    }
}

// ---------------------------------------------------------------------------
// One block per bucket (32 dsts). 8 half-waves stride the bucket's edge list
// (unroll 4 => 4 independent gather chains per half-wave). Accumulate into a
// padded LDS tile with ds_add_f32 (conflict-free banks), then write the
// 32x32 output tile + bias, coalesced float4.
// ---------------------------------------------------------------------------
__global__ void gather_kernel(const int2* __restrict__ bedge,
                              const int* __restrict__ boff,
                              const float* __restrict__ xt,
                              const float* __restrict__ bias,
                              float* __restrict__ out, int M) {
    __shared__ float acc[32 * 33];  // acc[dloc*33 + b], pad keeps banks clean
    int t = threadIdx.x;
    for (int j = t; j < 32 * 33; j += 256) acc[j] = 0.f;
    __syncthreads();

    int k = blockIdx.x;
    int o = boff[k];
    int n = boff[k + 1] - o;
    int hw = t >> 5;   // half-wave id 0..7
    int b  = t & 31;   // batch lane

    int i = hw;
    for (; i + 24 < n; i += 32) {
        int2 e0 = bedge[o + i];
        int2 e1 = bedge[o + i + 8];
        int2 e2 = bedge[o + i + 16];
        int2 e3 = bedge[o + i + 24];
        float p0 = __int_as_float(e0.y) * xt[(size_t)(e0.x & 0xFFFFF) * NB + b];
        float p1 = __int_as_float(e1.y) * xt[(size_t)(e1.x & 0xFFFFF) * NB + b];
        float p2 = __int_as_float(e2.y) * xt[(size_t)(e2.x & 0xFFFFF) * NB + b];
        float p3 = __int_as_float(e3.y) * xt[(size_t)(e3.x & 0xFFFFF) * NB + b];
        atomicAdd(&acc[(e0.x >> 20) * 33 + b], p0);
        atomicAdd(&acc[(e1.x >> 20) * 33 + b], p1);
        atomicAdd(&acc[(e2.x >> 20) * 33 + b], p2);
        atomicAdd(&acc[(e3.x >> 20) * 33 + b], p3);
    }
    for (; i < n; i += 8) {
        int2 e = bedge[o + i];
        float p = __int_as_float(e.y) * xt[(size_t)(e.x & 0xFFFFF) * NB + b];
        atomicAdd(&acc[(e.x >> 20) * 33 + b], p);
    }
    __syncthreads();

    // Epilogue: out[b2][m0+j0..j0+3] = acc[j][b2] + bias
    int b2 = t >> 3;
    int j0 = (t & 7) * 4;
    int m0 = k * 32;
    int m = m0 + j0;
    if ((M % 4 == 0) && (m + 3 < M)) {
        float4 bv = *(const float4*)&bias[m];
        float4 o4;
        o4.x = acc[(j0 + 0) * 33 + b2] + bv.x;
        o4.y = acc[(j0 + 1) * 33 + b2] + bv.y;
        o4.z = acc[(j0 + 2) * 33 + b2] + bv.z;
        o4.w = acc[(j0 + 3) * 33 + b2] + bv.w;
        *(float4*)&out[(size_t)b2 * M + m] = o4;
    } else {
        for (int q = 0; q < 4; q++)
            if (m + q < M)
                out[(size_t)b2 * M + m + q] = acc[(j0 + q) * 33 + b2] + bias[m + q];
    }
}

extern "C" void kernel_launch(void* const* d_in, const int* in_sizes, int n_in,
                              void* d_out, int out_size, void* d_ws, size_t ws_size,
                              hipStream_t stream) {
    const float* x       = (const float*)d_in[0];   // (B, N, 1) fp32
    const int*   indices = (const int*)  d_in[1];   // (2, NNZ) int32
    const float* vals    = (const float*)d_in[2];   // (NNZ,) fp32
    const float* bias    = (const float*)d_in[3];   // (M, 1) fp32
    float* out = (float*)d_out;                     // (B, M, 1) fp32

    int nnz = in_sizes[1] / 2;
    int N   = in_sizes[0] / NB;
    int M   = in_sizes[3];

    const int* src = indices;
    const int* dst = indices + nnz;

    int nb = (M + 31) / 32;  // buckets of 32 dsts

    // workspace layout
    float* xt     = (float*)d_ws;                   // N*32 floats (12.8 MB)
    int*   bcount = (int*)(xt + (size_t)N * NB);    // nb
    int*   boff   = bcount + nb;                    // nb+1
    int*   cursor = boff + nb + 1;                  // nb
    size_t intoff = (size_t)(3 * nb + 1);
    intoff = (intoff + 1) & ~(size_t)1;             // 8B-align bedge
    int2*  bedge  = (int2*)(bcount + intoff);       // nnz int2 (25.6 MB)

    hipMemsetAsync(bcount, 0, (size_t)nb * sizeof(int), stream);

    transpose_x_kernel<<<(N + 31) / 32, dim3(32, 8), 0, stream>>>(x, xt, N);

    int egrid = (nnz + 255) / 256;
    hist_kernel<<<egrid, 256, 0, stream>>>(dst, bcount, nnz);
    scan_kernel<<<1, 256, 0, stream>>>(bcount, boff, cursor, nb, nnz);
    partition_kernel<<<egrid, 256, 0, stream>>>(src, dst, vals, cursor, bedge, nnz);
    gather_kernel<<<nb, 256, 0, stream>>>(bedge, boff, xt, bias, out, M);
}

// Round 4
// 787.823 us; speedup vs baseline: 1.5087x; 1.5087x over previous
//
#include <hip/hip_runtime.h>

#define NB 32          // batch size B (fixed by problem)
#define MAXNB 3200     // LDS capacity for bucket counters (nb = ceil(M/32) = 3125)
#define HCHUNK 16384   // hist: edges per block
#define PCHUNK 32768   // partition: edges per block
#define PBT 1024       // partition: threads per block
#define MAXCHUNK 2048  // gather: staged edges per LDS chunk
// Packs dst%32 into bits [20:25) of the edge record => requires N <= 2^20.

// Device-scope load: carries coherence bits -> bypasses the per-CU L1.
// Random 128B gathers through L1 cap at ~0.5 TB/s (L1 miss-tracking limit,
// measured R1/R3); agent-scope loads queue misses in L2/fabric instead.
__device__ __forceinline__ float xld(const float* p) {
    return __hip_atomic_load(p, __ATOMIC_RELAXED, __HIP_MEMORY_SCOPE_AGENT);
}

// ---------------------------------------------------------------------------
// x (B, N) -> xt (N, B): 32x32 LDS tile transpose, coalesced read and write.
// ---------------------------------------------------------------------------
__global__ void transpose_x_kernel(const float* __restrict__ x,
                                   float* __restrict__ xt, int N) {
    __shared__ float tile[32][33];
    int n0 = blockIdx.x * 32;
    for (int i = threadIdx.y; i < 32; i += 8) {
        int n = n0 + threadIdx.x;
        tile[i][threadIdx.x] = (n < N) ? x[(size_t)i * N + n] : 0.f;
    }
    __syncthreads();
    for (int i = threadIdx.y; i < 32; i += 8) {
        int n = n0 + i;
        if (n < N) xt[(size_t)n * NB + threadIdx.x] = tile[threadIdx.x][i];
    }
}

// ---------------------------------------------------------------------------
// Bucket histogram via LDS: one global atomic per (bucket, block), not per edge.
// ---------------------------------------------------------------------------
__global__ void hist_kernel(const int* __restrict__ dst,
                            int* __restrict__ bcount, int nnz, int nb) {
    __shared__ int h[MAXNB];
    int t = threadIdx.x;
    for (int j = t; j < nb; j += 256) h[j] = 0;
    __syncthreads();
    int s0 = blockIdx.x * HCHUNK;
    int e0 = min(nnz, s0 + HCHUNK);
    for (int j = s0 + t; j < e0; j += 256) atomicAdd(&h[dst[j] >> 5], 1);
    __syncthreads();
    for (int j = t; j < nb; j += 256)
        if (h[j]) atomicAdd(&bcount[j], h[j]);
}

// ---------------------------------------------------------------------------
// Single-block exclusive scan over nb bucket counts -> boff, cursor=boff.
// ---------------------------------------------------------------------------
__global__ void scan_kernel(const int* __restrict__ bcount,
                            int* __restrict__ boff, int* __restrict__ cursor,
                            int nb, int nnz) {
    __shared__ int lds[256];
    int t = threadIdx.x;
    int chunk = (nb + 255) / 256;  // 13 for nb=3125
    int base = t * chunk;
    int v[16];
    int s = 0;
    for (int j = 0; j < chunk; j++) {
        int idx = base + j;
        v[j] = (idx < nb) ? bcount[idx] : 0;
        s += v[j];
    }
    lds[t] = s;
    __syncthreads();
    for (int d = 1; d < 256; d <<= 1) {
        int u = (t >= d) ? lds[t - d] : 0;
        __syncthreads();
        lds[t] += u;
        __syncthreads();
    }
    int ex = lds[t] - s;
    for (int j = 0; j < chunk; j++) {
        int idx = base + j;
        if (idx < nb) {
            boff[idx] = ex;
            cursor[idx] = ex;
            ex += v[j];
        }
    }
    if (t == 255) boff[nb] = nnz;
}

// ---------------------------------------------------------------------------
// Reservation-based partition. Per 32K-edge block: LDS hist -> one global
// atomicAdd per bucket reserves a contiguous run -> grouped writes. Runs are
// single-block-owned => full-line writebacks, no cross-XCD line sharing,
// no per-edge global-cursor contention.
// ---------------------------------------------------------------------------
__global__ void partition_kernel(const int* __restrict__ src,
                                 const int* __restrict__ dst,
                                 const float* __restrict__ vals,
                                 int* __restrict__ cursor,
                                 int2* __restrict__ bedge, int nnz, int nb) {
    __shared__ int h[MAXNB];
    __shared__ int basel[MAXNB];
    int t = threadIdx.x;
    for (int j = t; j < nb; j += PBT) h[j] = 0;
    __syncthreads();
    int s0 = blockIdx.x * PCHUNK;
    int e0 = min(nnz, s0 + PCHUNK);
    for (int j = s0 + t; j < e0; j += PBT) atomicAdd(&h[dst[j] >> 5], 1);
    __syncthreads();
    for (int j = t; j < nb; j += PBT) {
        int c = h[j];
        basel[j] = c ? atomicAdd(&cursor[j], c) : 0;
        h[j] = 0;  // reuse as block-local cursor
    }
    __syncthreads();
    for (int j = s0 + t; j < e0; j += PBT) {
        int d = dst[j];
        int bk = d >> 5;
        int pos = basel[bk] + atomicAdd(&h[bk], 1);
        bedge[pos] = make_int2(src[j] | ((d & 31) << 20), __float_as_int(vals[j]));
    }
}

// ---------------------------------------------------------------------------
// One block per bucket (32 dsts). Edges staged into LDS (kills the
// bedge->xt dependent chain), then 8 half-waves each process a contiguous
// segment with unroll 8 => 8 independent L1-bypassing xt gathers in flight
// per half-wave. Accumulate via ds_add into a padded 32x33 tile
// (bank = (dloc + b) % 32 -> conflict-free), coalesced epilogue + bias.
// ---------------------------------------------------------------------------
__global__ void gather_kernel(const int2* __restrict__ bedge,
                              const int* __restrict__ boff,
                              const float* __restrict__ xt,
                              const float* __restrict__ bias,
                              float* __restrict__ out, int M) {
    __shared__ int4 est4[MAXCHUNK / 2];  // 16 KB edge staging
    __shared__ float acc[32 * 33];       // acc[dloc*33 + b]
    int2* est2 = (int2*)est4;
    int t = threadIdx.x;
    for (int j = t; j < 32 * 33; j += 256) acc[j] = 0.f;

    int k = blockIdx.x;
    int o = boff[k];
    int n = boff[k + 1] - o;
    int hw = t >> 5;  // half-wave id 0..7
    int b = t & 31;   // batch lane

    for (int c0 = 0; c0 < n; c0 += MAXCHUNK) {
        int nc = min(n - c0, MAXCHUNK);
        __syncthreads();  // staging reuse + (first iter) acc-zero visibility
        for (int j = t; j < nc; j += 256) est2[j] = bedge[o + c0 + j];
        __syncthreads();

        int seg = ((nc + 15) >> 4) << 1;  // even => int4-aligned segment start
        int st = hw * seg;
        int en = min(st + seg, nc);
        int i = st;
        for (; i + 8 <= en; i += 8) {
            int g = i >> 1;
            int4 q0 = est4[g + 0];
            int4 q1 = est4[g + 1];
            int4 q2 = est4[g + 2];
            int4 q3 = est4[g + 3];
            // 8 independent L1-bypass gathers
            float x0 = xld(&xt[(size_t)(q0.x & 0xFFFFF) * NB + b]);
            float x1 = xld(&xt[(size_t)(q0.z & 0xFFFFF) * NB + b]);
            float x2 = xld(&xt[(size_t)(q1.x & 0xFFFFF) * NB + b]);
            float x3 = xld(&xt[(size_t)(q1.z & 0xFFFFF) * NB + b]);
            float x4 = xld(&xt[(size_t)(q2.x & 0xFFFFF) * NB + b]);
            float x5 = xld(&xt[(size_t)(q2.z & 0xFFFFF) * NB + b]);
            float x6 = xld(&xt[(size_t)(q3.x & 0xFFFFF) * NB + b]);
            float x7 = xld(&xt[(size_t)(q3.z & 0xFFFFF) * NB + b]);
            atomicAdd(&acc[((unsigned)q0.x >> 20) * 33 + b], __int_as_float(q0.y) * x0);
            atomicAdd(&acc[((unsigned)q0.z >> 20) * 33 + b], __int_as_float(q0.w) * x1);
            atomicAdd(&acc[((unsigned)q1.x >> 20) * 33 + b], __int_as_float(q1.y) * x2);
            atomicAdd(&acc[((unsigned)q1.z >> 20) * 33 + b], __int_as_float(q1.w) * x3);
            atomicAdd(&acc[((unsigned)q2.x >> 20) * 33 + b], __int_as_float(q2.y) * x4);
            atomicAdd(&acc[((unsigned)q2.z >> 20) * 33 + b], __int_as_float(q2.w) * x5);
            atomicAdd(&acc[((unsigned)q3.x >> 20) * 33 + b], __int_as_float(q3.y) * x6);
            atomicAdd(&acc[((unsigned)q3.z >> 20) * 33 + b], __int_as_float(q3.w) * x7);
        }
        for (; i < en; i++) {
            int2 e = est2[i];
            float xv = xld(&xt[(size_t)(e.x & 0xFFFFF) * NB + b]);
            atomicAdd(&acc[((unsigned)e.x >> 20) * 33 + b], __int_as_float(e.y) * xv);
        }
    }
    __syncthreads();

    // Epilogue: out[b2][m0+j0..j0+3] = acc[j][b2] + bias (M % 4 == 0 path hot)
    int b2 = t >> 3;
    int j0 = (t & 7) * 4;
    int m0 = k * 32;
    int m = m0 + j0;
    if ((M % 4 == 0) && (m + 3 < M)) {
        float4 bv = *(const float4*)&bias[m];
        float4 o4;
        o4.x = acc[(j0 + 0) * 33 + b2] + bv.x;
        o4.y = acc[(j0 + 1) * 33 + b2] + bv.y;
        o4.z = acc[(j0 + 2) * 33 + b2] + bv.z;
        o4.w = acc[(j0 + 3) * 33 + b2] + bv.w;
        *(float4*)&out[(size_t)b2 * M + m] = o4;
    } else {
        for (int q = 0; q < 4; q++)
            if (m + q < M)
                out[(size_t)b2 * M + m + q] = acc[(j0 + q) * 33 + b2] + bias[m + q];
    }
}

extern "C" void kernel_launch(void* const* d_in, const int* in_sizes, int n_in,
                              void* d_out, int out_size, void* d_ws, size_t ws_size,
                              hipStream_t stream) {
    const float* x       = (const float*)d_in[0];   // (B, N, 1) fp32
    const int*   indices = (const int*)  d_in[1];   // (2, NNZ) int32
    const float* vals    = (const float*)d_in[2];   // (NNZ,) fp32
    const float* bias    = (const float*)d_in[3];   // (M, 1) fp32
    float* out = (float*)d_out;                     // (B, M, 1) fp32

    int nnz = in_sizes[1] / 2;
    int N   = in_sizes[0] / NB;
    int M   = in_sizes[3];

    const int* src = indices;
    const int* dst = indices + nnz;

    int nb = (M + 31) / 32;  // 3125 buckets of 32 dsts

    // workspace layout
    float* xt     = (float*)d_ws;                   // N*32 floats (12.8 MB)
    int*   bcount = (int*)(xt + (size_t)N * NB);    // nb
    int*   boff   = bcount + nb;                    // nb+1
    int*   cursor = boff + nb + 1;                  // nb
    size_t intoff = (size_t)(3 * nb + 1);
    intoff = (intoff + 3) & ~(size_t)3;             // 16B-align bedge
    int2*  bedge  = (int2*)(bcount + intoff);       // nnz int2 (25.6 MB)

    hipMemsetAsync(bcount, 0, (size_t)nb * sizeof(int), stream);

    transpose_x_kernel<<<(N + 31) / 32, dim3(32, 8), 0, stream>>>(x, xt, N);

    hist_kernel<<<(nnz + HCHUNK - 1) / HCHUNK, 256, 0, stream>>>(dst, bcount,
                                                                 nnz, nb);
    scan_kernel<<<1, 256, 0, stream>>>(bcount, boff, cursor, nb, nnz);
    partition_kernel<<<(nnz + PCHUNK - 1) / PCHUNK, PBT, 0, stream>>>(
        src, dst, vals, cursor, bedge, nnz, nb);
    gather_kernel<<<nb, 256, 0, stream>>>(bedge, boff, xt, bias, out, M);
}